// Round 3
// baseline (10587.420 us; speedup 1.0000x reference)
//
#include <hip/hip_runtime.h>
#include <hip/hip_bf16.h>

using bf16x8 = __attribute__((ext_vector_type(8))) __bf16;
using f32x4  = __attribute__((ext_vector_type(4))) float;

constexpr int NB = 32;     // batch
constexpr int NS = 512;    // seq len
constexpr int NE = 512;    // embed dim
constexpr int NH = 1024;   // hidden
constexpr int NV = 5000;   // vocab
constexpr int NG = 4096;   // 4*NH (gates: i,f,g,o)

// ---------- bf16 helpers (raw ushort storage) ----------
__device__ __forceinline__ float blo(unsigned u) {
    union { unsigned i; float f; } v; v.i = u << 16; return v.f;
}
__device__ __forceinline__ float bhi(unsigned u) {
    union { unsigned i; float f; } v; v.i = u & 0xffff0000u; return v.f;
}
__device__ __forceinline__ unsigned short f2bf(float f) {  // round-to-nearest-even
    union { float f; unsigned i; } v; v.f = f;
    unsigned r = v.i + 0x7fffu + ((v.i >> 16) & 1u);
    return (unsigned short)(r >> 16);
}
// pack 8 fp32 -> 8 bf16 (as uint4, shorts in index order, little-endian)
__device__ __forceinline__ uint4 pack8(float4 a, float4 b) {
    uint4 r;
    r.x = (unsigned)f2bf(a.x) | ((unsigned)f2bf(a.y) << 16);
    r.y = (unsigned)f2bf(a.z) | ((unsigned)f2bf(a.w) << 16);
    r.z = (unsigned)f2bf(b.x) | ((unsigned)f2bf(b.y) << 16);
    r.w = (unsigned)f2bf(b.z) | ((unsigned)f2bf(b.w) << 16);
    return r;
}

// =====================================================================
// GEMM1: xg[m, g] = sum_e emb[x[m]][e] * W_ih[g][e] + b_ih[g] + b_hh[g]
// fp32 inputs converted to bf16 at LDS staging; bf16 MFMA; bf16 xg out.
// M=16384, N=4096, K=512.  64x64 tile, BK=32, 4 waves (2x2 of 32x32).
// =====================================================================
__global__ __launch_bounds__(256) void k_embed_gemm(
    const int* __restrict__ x,
    const float* __restrict__ emb,
    const float* __restrict__ W_ih,
    const float* __restrict__ b_ih,
    const float* __restrict__ b_hh,
    unsigned short* __restrict__ xg)
{
    constexpr int BK = 32, LDP = BK + 8;
    __shared__ __align__(16) unsigned short Ash[64 * LDP];
    __shared__ __align__(16) unsigned short Bsh[64 * LDP];
    __shared__ int ids[64];

    const int tid = threadIdx.x;
    const int m0 = blockIdx.y * 64;
    const int n0 = blockIdx.x * 64;
    if (tid < 64) ids[tid] = x[m0 + tid];
    __syncthreads();

    const int wave = tid >> 6, lane = tid & 63;
    const int wm = (wave >> 1) * 32, wn = (wave & 1) * 32;
    const int fr = lane & 15, kq = lane >> 4;

    const int sr = tid >> 2;          // staging row 0..63
    const int sc = (tid & 3) * 8;     // staging col (elements), covers BK=32

    f32x4 acc[2][2] = {};

    for (int k0 = 0; k0 < NE; k0 += BK) {
        const float* ap = emb + (size_t)ids[sr] * NE + k0 + sc;
        const float* bp = W_ih + (size_t)(n0 + sr) * NE + k0 + sc;
        float4 af0 = *(const float4*)ap, af1 = *(const float4*)(ap + 4);
        float4 bf0 = *(const float4*)bp, bf1 = *(const float4*)(bp + 4);
        *(uint4*)(Ash + sr * LDP + sc) = pack8(af0, af1);
        *(uint4*)(Bsh + sr * LDP + sc) = pack8(bf0, bf1);
        __syncthreads();
        bf16x8 a0 = *(const bf16x8*)(Ash + (wm + fr) * LDP + kq * 8);
        bf16x8 a1 = *(const bf16x8*)(Ash + (wm + 16 + fr) * LDP + kq * 8);
        bf16x8 b0 = *(const bf16x8*)(Bsh + (wn + fr) * LDP + kq * 8);
        bf16x8 b1 = *(const bf16x8*)(Bsh + (wn + 16 + fr) * LDP + kq * 8);
        acc[0][0] = __builtin_amdgcn_mfma_f32_16x16x32_bf16(a0, b0, acc[0][0], 0, 0, 0);
        acc[0][1] = __builtin_amdgcn_mfma_f32_16x16x32_bf16(a0, b1, acc[0][1], 0, 0, 0);
        acc[1][0] = __builtin_amdgcn_mfma_f32_16x16x32_bf16(a1, b0, acc[1][0], 0, 0, 0);
        acc[1][1] = __builtin_amdgcn_mfma_f32_16x16x32_bf16(a1, b1, acc[1][1], 0, 0, 0);
        __syncthreads();
    }

    for (int i = 0; i < 2; ++i)
        for (int j = 0; j < 2; ++j) {
            const int row = m0 + wm + i * 16 + kq * 4;   // C/D: row=(lane>>4)*4+reg
            const int col = n0 + wn + j * 16 + fr;       //      col=lane&15
            const float bias = b_ih[col] + b_hh[col];
            for (int r = 0; r < 4; ++r)
                xg[(size_t)(row + r) * NG + col] = f2bf(acc[i][j][r] + bias);
        }
}

// =====================================================================
// LSTM step t: gates[b,g] = xg[b,t,g] + h_{t-1}[b,:] . W_hh[g,:]
// 256 blocks; block owns 4 hidden units (16 gate rows).  fp32 VALU dots.
// k streamed in CK=256 chunks, double-buffered LDS (~53 KB total),
// register prefetch so global latency overlaps the dot.
// =====================================================================
__global__ __launch_bounds__(256) void k_lstm_step(
    const unsigned short* __restrict__ xg,   // bf16 [B,S,4H]
    const float* __restrict__ W_hh,          // fp32 [4H,H]
    unsigned short* __restrict__ hs,         // bf16 [B,S,H]
    float* __restrict__ c,                   // fp32 [B,H]
    int t)
{
    constexpr int CK = 256, LDC = CK + 8, NC = NH / CK;  // 4 chunks
    __shared__ __align__(16) unsigned short hch[2][32 * LDC];  // 33,792 B
    __shared__ __align__(16) unsigned short wch[2][16 * LDC];  // 16,896 B
    __shared__ float gsh[16 * 32];                             //  2,048 B

    const int tid = threadIdx.x;
    const int j0 = blockIdx.x * 4;

    // W staging coords: 16 rows x 256 floats; 16 floats per thread
    const int rr_s = tid >> 4;             // 0..15
    const int foff = (tid & 15) * 16;      // 0..240
    const int grow_s = (rr_s >> 2) * NH + j0 + (rr_s & 3);
    const float* wsrc = W_hh + (size_t)grow_s * NH;

    // ---- stage chunk 0 ----
    for (int i = 0; i < 4; ++i) {
        const int ch = tid + i * 256;         // 0..1023
        const int b = ch >> 5;                // 32 uint4 per row-chunk
        const int off = (ch & 31) * 8;
        uint4 v = make_uint4(0u, 0u, 0u, 0u);
        if (t > 0) v = *(const uint4*)(hs + ((size_t)b * NS + (t - 1)) * NH + off);
        *(uint4*)(&hch[0][b * LDC + off]) = v;
    }
    {
        float4 f0 = *(const float4*)(wsrc + foff);
        float4 f1 = *(const float4*)(wsrc + foff + 4);
        float4 f2 = *(const float4*)(wsrc + foff + 8);
        float4 f3 = *(const float4*)(wsrc + foff + 12);
        *(uint4*)(&wch[0][rr_s * LDC + foff])     = pack8(f0, f1);
        *(uint4*)(&wch[0][rr_s * LDC + foff + 8]) = pack8(f2, f3);
    }
    __syncthreads();

    const int rr = tid & 15;     // gate row 0..15
    const int bq = tid >> 4;     // batches bq and bq+16
    float a0 = 0.f, a1 = 0.f, a2 = 0.f, a3 = 0.f;

    for (int cidx = 0; cidx < NC; ++cidx) {
        const int cur = cidx & 1, nxt = cur ^ 1;
        const bool more = (cidx + 1 < NC);
        uint4 hv[4]; float4 wf[4];
        if (more) {                       // prefetch next chunk into registers
            const int kc = (cidx + 1) * CK;
            for (int i = 0; i < 4; ++i) {
                const int ch = tid + i * 256;
                const int b = ch >> 5;
                const int off = (ch & 31) * 8;
                hv[i] = make_uint4(0u, 0u, 0u, 0u);
                if (t > 0)
                    hv[i] = *(const uint4*)(hs + ((size_t)b * NS + (t - 1)) * NH + kc + off);
            }
            for (int i = 0; i < 4; ++i)
                wf[i] = *(const float4*)(wsrc + kc + foff + i * 4);
        }
        // dot over current chunk (LDS)
        const unsigned short* wp  = &wch[cur][rr * LDC];
        const unsigned short* hp0 = &hch[cur][bq * LDC];
        const unsigned short* hp1 = &hch[cur][(bq + 16) * LDC];
#pragma unroll 4
        for (int k = 0; k < CK; k += 8) {
            const uint4 wv = *(const uint4*)(wp + k);
            const uint4 u0 = *(const uint4*)(hp0 + k);
            const uint4 u1 = *(const uint4*)(hp1 + k);
            const float w0 = blo(wv.x), w1 = bhi(wv.x), w2 = blo(wv.y), w3 = bhi(wv.y);
            const float w4 = blo(wv.z), w5 = bhi(wv.z), w6 = blo(wv.w), w7 = bhi(wv.w);
            a0 += w0 * blo(u0.x) + w1 * bhi(u0.x) + w2 * blo(u0.y) + w3 * bhi(u0.y);
            a1 += w4 * blo(u0.z) + w5 * bhi(u0.z) + w6 * blo(u0.w) + w7 * bhi(u0.w);
            a2 += w0 * blo(u1.x) + w1 * bhi(u1.x) + w2 * blo(u1.y) + w3 * bhi(u1.y);
            a3 += w4 * blo(u1.z) + w5 * bhi(u1.z) + w6 * blo(u1.w) + w7 * bhi(u1.w);
        }
        if (more) {                       // commit prefetched chunk to LDS
            for (int i = 0; i < 4; ++i) {
                const int ch = tid + i * 256;
                const int b = ch >> 5;
                const int off = (ch & 31) * 8;
                *(uint4*)(&hch[nxt][b * LDC + off]) = hv[i];
            }
            *(uint4*)(&wch[nxt][rr_s * LDC + foff])     = pack8(wf[0], wf[1]);
            *(uint4*)(&wch[nxt][rr_s * LDC + foff + 8]) = pack8(wf[2], wf[3]);
        }
        __syncthreads();
    }

    const int grow = (rr >> 2) * NH + j0 + (rr & 3);
    {
        const int b0 = bq, b1 = bq + 16;
        const unsigned xg0 = xg[((size_t)b0 * NS + t) * NG + grow];
        const unsigned xg1 = xg[((size_t)b1 * NS + t) * NG + grow];
        gsh[rr * 32 + b0] = (a0 + a1) + blo(xg0);
        gsh[rr * 32 + b1] = (a2 + a3) + blo(xg1);
    }
    __syncthreads();

    if (tid < 128) {
        const int b = tid & 31, j = tid >> 5;   // j in 0..3
        float ig = gsh[(0 * 4 + j) * 32 + b];
        float fg = gsh[(1 * 4 + j) * 32 + b];
        float gg = gsh[(2 * 4 + j) * 32 + b];
        float og = gsh[(3 * 4 + j) * 32 + b];
        ig = 1.f / (1.f + __expf(-ig));
        fg = 1.f / (1.f + __expf(-fg));
        og = 1.f / (1.f + __expf(-og));
        gg = tanhf(gg);
        const int jg = j0 + j;
        const float cp = (t == 0) ? 0.f : c[b * NH + jg];
        const float cn = fg * cp + ig * gg;
        const float hn = og * tanhf(cn);
        c[b * NH + jg] = cn;
        hs[((size_t)b * NS + t) * NH + jg] = f2bf(hn);
    }
}

// =====================================================================
// GEMM3: out[m, v] = hs[m,:] . W_fc[v,:] + b_fc[v]   (fp32 out)
// M=16384, N=5000 (edge tiles), K=1024.
// =====================================================================
__global__ __launch_bounds__(256) void k_logits_gemm(
    const unsigned short* __restrict__ hs,   // bf16
    const float* __restrict__ W_fc,          // fp32
    const float* __restrict__ b_fc,          // fp32
    float* __restrict__ out)                 // fp32
{
    constexpr int BK = 32, LDP = BK + 8;
    __shared__ __align__(16) unsigned short Ash[64 * LDP];
    __shared__ __align__(16) unsigned short Bsh[64 * LDP];

    const int tid = threadIdx.x;
    const int m0 = blockIdx.y * 64;
    const int n0 = blockIdx.x * 64;

    const int wave = tid >> 6, lane = tid & 63;
    const int wm = (wave >> 1) * 32, wn = (wave & 1) * 32;
    const int fr = lane & 15, kq = lane >> 4;

    const int sr = tid >> 2;
    const int sc = (tid & 3) * 8;
    const int brow = min(n0 + sr, NV - 1);   // clamp edge-tile rows

    f32x4 acc[2][2] = {};

    for (int k0 = 0; k0 < NH; k0 += BK) {
        const float* bp = W_fc + (size_t)brow * NH + k0 + sc;
        float4 bf0 = *(const float4*)bp, bf1 = *(const float4*)(bp + 4);
        *(uint4*)(Ash + sr * LDP + sc) =
            *(const uint4*)(hs + (size_t)(m0 + sr) * NH + k0 + sc);
        *(uint4*)(Bsh + sr * LDP + sc) = pack8(bf0, bf1);
        __syncthreads();
        bf16x8 a0 = *(const bf16x8*)(Ash + (wm + fr) * LDP + kq * 8);
        bf16x8 a1 = *(const bf16x8*)(Ash + (wm + 16 + fr) * LDP + kq * 8);
        bf16x8 b0 = *(const bf16x8*)(Bsh + (wn + fr) * LDP + kq * 8);
        bf16x8 b1 = *(const bf16x8*)(Bsh + (wn + 16 + fr) * LDP + kq * 8);
        acc[0][0] = __builtin_amdgcn_mfma_f32_16x16x32_bf16(a0, b0, acc[0][0], 0, 0, 0);
        acc[0][1] = __builtin_amdgcn_mfma_f32_16x16x32_bf16(a0, b1, acc[0][1], 0, 0, 0);
        acc[1][0] = __builtin_amdgcn_mfma_f32_16x16x32_bf16(a1, b0, acc[1][0], 0, 0, 0);
        acc[1][1] = __builtin_amdgcn_mfma_f32_16x16x32_bf16(a1, b1, acc[1][1], 0, 0, 0);
        __syncthreads();
    }

    for (int i = 0; i < 2; ++i)
        for (int j = 0; j < 2; ++j) {
            const int row = m0 + wm + i * 16 + kq * 4;
            const int col = n0 + wn + j * 16 + fr;
            if (col < NV) {
                const float bias = b_fc[col];
                for (int r = 0; r < 4; ++r)
                    out[(size_t)(row + r) * NV + col] = acc[i][j][r] + bias;
            }
        }
}

// =====================================================================
extern "C" void kernel_launch(void* const* d_in, const int* in_sizes, int n_in,
                              void* d_out, int out_size, void* d_ws, size_t ws_size,
                              hipStream_t stream)
{
    const int*   x    = (const int*)d_in[0];
    const float* emb  = (const float*)d_in[1];
    const float* W_ih = (const float*)d_in[2];
    const float* W_hh = (const float*)d_in[3];
    const float* b_ih = (const float*)d_in[4];
    const float* b_hh = (const float*)d_in[5];
    const float* W_fc = (const float*)d_in[6];
    const float* b_fc = (const float*)d_in[7];
    float*       out  = (float*)d_out;

    // workspace: xg bf16 (134.2MB) | hs bf16 (33.6MB) | c fp32 (128KB)
    char* w = (char*)d_ws;
    const size_t XG_BYTES = (size_t)NB * NS * NG * 2;
    const size_t HS_BYTES = (size_t)NB * NS * NH * 2;
    unsigned short* xg  = (unsigned short*)w;
    unsigned short* hsb = (unsigned short*)(w + XG_BYTES);
    float*          c   = (float*)(w + XG_BYTES + HS_BYTES);

    k_embed_gemm<<<dim3(NG / 64, (NB * NS) / 64), 256, 0, stream>>>(
        x, emb, W_ih, b_ih, b_hh, xg);

    for (int t = 0; t < NS; ++t)
        k_lstm_step<<<dim3(NH / 4), 256, 0, stream>>>(xg, W_hh, hsb, c, t);

    k_logits_gemm<<<dim3((NV + 63) / 64, (NB * NS) / 64), 256, 0, stream>>>(
        hsb, W_fc, b_fc, out);
}

// Round 4
// 5420.019 us; speedup vs baseline: 1.9534x; 1.9534x over previous
//
#include <hip/hip_runtime.h>
#include <hip/hip_bf16.h>

using bf16x8 = __attribute__((ext_vector_type(8))) __bf16;
using f32x4  = __attribute__((ext_vector_type(4))) float;

constexpr int NB = 32;     // batch
constexpr int NS = 512;    // seq len
constexpr int NE = 512;    // embed dim
constexpr int NH = 1024;   // hidden
constexpr int NV = 5000;   // vocab
constexpr int NG = 4096;   // 4*NH (gates: i,f,g,o)

// ---------- bf16 helpers (raw ushort storage) ----------
__device__ __forceinline__ float blo(unsigned u) {
    union { unsigned i; float f; } v; v.i = u << 16; return v.f;
}
__device__ __forceinline__ unsigned short f2bf(float f) {  // round-to-nearest-even
    union { float f; unsigned i; } v; v.f = f;
    unsigned r = v.i + 0x7fffu + ((v.i >> 16) & 1u);
    return (unsigned short)(r >> 16);
}
// pack 8 fp32 -> 8 bf16 (as uint4, shorts in index order, little-endian)
__device__ __forceinline__ uint4 pack8(float4 a, float4 b) {
    uint4 r;
    r.x = (unsigned)f2bf(a.x) | ((unsigned)f2bf(a.y) << 16);
    r.y = (unsigned)f2bf(a.z) | ((unsigned)f2bf(a.w) << 16);
    r.z = (unsigned)f2bf(b.x) | ((unsigned)f2bf(b.y) << 16);
    r.w = (unsigned)f2bf(b.z) | ((unsigned)f2bf(b.w) << 16);
    return r;
}

// =====================================================================
// GEMM1: xg[m, g] = sum_e emb[x[m]][e] * W_ih[g][e] + b_ih[g] + b_hh[g]
// fp32 inputs converted to bf16 at LDS staging; bf16 MFMA; bf16 xg out.
// M=16384, N=4096, K=512.  64x64 tile, BK=32, 4 waves (2x2 of 32x32).
// =====================================================================
__global__ __launch_bounds__(256) void k_embed_gemm(
    const int* __restrict__ x,
    const float* __restrict__ emb,
    const float* __restrict__ W_ih,
    const float* __restrict__ b_ih,
    const float* __restrict__ b_hh,
    unsigned short* __restrict__ xg)
{
    constexpr int BK = 32, LDP = BK + 8;
    __shared__ __align__(16) unsigned short Ash[64 * LDP];
    __shared__ __align__(16) unsigned short Bsh[64 * LDP];
    __shared__ int ids[64];

    const int tid = threadIdx.x;
    const int m0 = blockIdx.y * 64;
    const int n0 = blockIdx.x * 64;
    if (tid < 64) ids[tid] = x[m0 + tid];
    __syncthreads();

    const int wave = tid >> 6, lane = tid & 63;
    const int wm = (wave >> 1) * 32, wn = (wave & 1) * 32;
    const int fr = lane & 15, kq = lane >> 4;

    const int sr = tid >> 2;          // staging row 0..63
    const int sc = (tid & 3) * 8;     // staging col (elements), covers BK=32

    f32x4 acc[2][2] = {};

    for (int k0 = 0; k0 < NE; k0 += BK) {
        const float* ap = emb + (size_t)ids[sr] * NE + k0 + sc;
        const float* bp = W_ih + (size_t)(n0 + sr) * NE + k0 + sc;
        float4 af0 = *(const float4*)ap, af1 = *(const float4*)(ap + 4);
        float4 bf0 = *(const float4*)bp, bf1 = *(const float4*)(bp + 4);
        *(uint4*)(Ash + sr * LDP + sc) = pack8(af0, af1);
        *(uint4*)(Bsh + sr * LDP + sc) = pack8(bf0, bf1);
        __syncthreads();
        bf16x8 a0 = *(const bf16x8*)(Ash + (wm + fr) * LDP + kq * 8);
        bf16x8 a1 = *(const bf16x8*)(Ash + (wm + 16 + fr) * LDP + kq * 8);
        bf16x8 b0 = *(const bf16x8*)(Bsh + (wn + fr) * LDP + kq * 8);
        bf16x8 b1 = *(const bf16x8*)(Bsh + (wn + 16 + fr) * LDP + kq * 8);
        acc[0][0] = __builtin_amdgcn_mfma_f32_16x16x32_bf16(a0, b0, acc[0][0], 0, 0, 0);
        acc[0][1] = __builtin_amdgcn_mfma_f32_16x16x32_bf16(a0, b1, acc[0][1], 0, 0, 0);
        acc[1][0] = __builtin_amdgcn_mfma_f32_16x16x32_bf16(a1, b0, acc[1][0], 0, 0, 0);
        acc[1][1] = __builtin_amdgcn_mfma_f32_16x16x32_bf16(a1, b1, acc[1][1], 0, 0, 0);
        __syncthreads();
    }

    for (int i = 0; i < 2; ++i)
        for (int j = 0; j < 2; ++j) {
            const int row = m0 + wm + i * 16 + kq * 4;   // C/D: row=(lane>>4)*4+reg
            const int col = n0 + wn + j * 16 + fr;       //      col=lane&15
            const float bias = b_ih[col] + b_hh[col];
            for (int r = 0; r < 4; ++r)
                xg[(size_t)(row + r) * NG + col] = f2bf(acc[i][j][r] + bias);
        }
}

// =====================================================================
// LSTM step t (MFMA version): gates[32,16cols] = h[32,1024] . W_hh16^T
// 256 blocks; block owns 4 hidden units -> 16 gate cols {i,f,g,o}x4.
// 4 waves K-split (256 each); register-direct fragments (no LDS staging):
//   A-frag: 16B contiguous bf16 loads from hs (L2/LLC-hot)
//   B-frag: 8 fp32 loads from W_hh + RNE pack (per-lane row pointer)
// Cross-wave K-reduce via padded LDS; fused activations + c/h update.
// =====================================================================
__global__ __launch_bounds__(256) void k_lstm_step(
    const unsigned short* __restrict__ xg,   // bf16 [B,S,4H]
    const float* __restrict__ W_hh,          // fp32 [4H,H]
    unsigned short* __restrict__ hs,         // bf16 [B,S,H]
    float* __restrict__ c,                   // fp32 [B,H]
    int t)
{
    __shared__ float red[4 * 2 * 16 * 17];   // [wave][mtile][row][col] pad17 = 8704 B

    const int tid = threadIdx.x;
    const int wave = tid >> 6, lane = tid & 63;
    const int fr = lane & 15, kq = lane >> 4;
    const int j0 = blockIdx.x * 4;           // this block's 4 hidden units

    // B column fr -> gate g = fr>>2, unit u = fr&3 -> W_hh row g*NH + j0 + u
    const float* wrow = W_hh + (size_t)((fr >> 2) * NH + j0 + (fr & 3)) * NH;
    const int kbase = wave * 256;            // this wave's K segment

    // ---- A fragments: h_{t-1} rows (batches fr and fr+16), 8 K-steps ----
    bf16x8 afrag[2][8] = {};
    if (t > 0) {
        const unsigned short* h0 = hs + ((size_t)fr        * NS + (t - 1)) * NH + kbase + kq * 8;
        const unsigned short* h1 = hs + ((size_t)(fr + 16) * NS + (t - 1)) * NH + kbase + kq * 8;
#pragma unroll
        for (int ks = 0; ks < 8; ++ks) {
            afrag[0][ks] = *(const bf16x8*)(h0 + ks * 32);
            afrag[1][ks] = *(const bf16x8*)(h1 + ks * 32);
        }
    }

    // ---- MFMA over this wave's K segment ----
    f32x4 acc0 = {}, acc1 = {};
#pragma unroll
    for (int ks = 0; ks < 8; ++ks) {
        const float* wp = wrow + kbase + ks * 32 + kq * 8;
        float4 w0 = *(const float4*)wp, w1 = *(const float4*)(wp + 4);
        uint4 p = pack8(w0, w1);
        bf16x8 bfr = *(bf16x8*)&p;
        acc0 = __builtin_amdgcn_mfma_f32_16x16x32_bf16(afrag[0][ks], bfr, acc0, 0, 0, 0);
        acc1 = __builtin_amdgcn_mfma_f32_16x16x32_bf16(afrag[1][ks], bfr, acc1, 0, 0, 0);
    }

    // ---- cross-wave reduction: C/D layout row=kq*4+r, col=fr ----
#pragma unroll
    for (int r = 0; r < 4; ++r) {
        red[((wave * 2 + 0) * 16 + kq * 4 + r) * 17 + fr] = acc0[r];
        red[((wave * 2 + 1) * 16 + kq * 4 + r) * 17 + fr] = acc1[r];
    }
    __syncthreads();

    // ---- activations + state update: 128 threads = 32 batches x 4 units ----
    if (tid < 128) {
        const int b = tid & 31, u = tid >> 5;
        const int mt = b >> 4, row = b & 15;
        float g4[4];
#pragma unroll
        for (int g = 0; g < 4; ++g) {
            const int col = g * 4 + u;
            float s = 0.f;
#pragma unroll
            for (int w = 0; w < 4; ++w)
                s += red[((w * 2 + mt) * 16 + row) * 17 + col];
            s += blo((unsigned)xg[((size_t)b * NS + t) * NG + g * NH + j0 + u]);
            g4[g] = s;
        }
        const float ig = 1.f / (1.f + __expf(-g4[0]));
        const float fg = 1.f / (1.f + __expf(-g4[1]));
        const float gg = tanhf(g4[2]);
        const float og = 1.f / (1.f + __expf(-g4[3]));
        const int jg = j0 + u;
        const float cp = (t == 0) ? 0.f : c[b * NH + jg];
        const float cn = fg * cp + ig * gg;
        c[b * NH + jg] = cn;
        hs[((size_t)b * NS + t) * NH + jg] = f2bf(og * tanhf(cn));
    }
}

// =====================================================================
// GEMM3: out[m, v] = hs[m,:] . W_fc[v,:] + b_fc[v]   (fp32 out)
// M=16384, N=5000 (edge tiles), K=1024.
// =====================================================================
__global__ __launch_bounds__(256) void k_logits_gemm(
    const unsigned short* __restrict__ hs,   // bf16
    const float* __restrict__ W_fc,          // fp32
    const float* __restrict__ b_fc,          // fp32
    float* __restrict__ out)                 // fp32
{
    constexpr int BK = 32, LDP = BK + 8;
    __shared__ __align__(16) unsigned short Ash[64 * LDP];
    __shared__ __align__(16) unsigned short Bsh[64 * LDP];

    const int tid = threadIdx.x;
    const int m0 = blockIdx.y * 64;
    const int n0 = blockIdx.x * 64;

    const int wave = tid >> 6, lane = tid & 63;
    const int wm = (wave >> 1) * 32, wn = (wave & 1) * 32;
    const int fr = lane & 15, kq = lane >> 4;

    const int sr = tid >> 2;
    const int sc = (tid & 3) * 8;
    const int brow = min(n0 + sr, NV - 1);   // clamp edge-tile rows

    f32x4 acc[2][2] = {};

    for (int k0 = 0; k0 < NH; k0 += BK) {
        const float* bp = W_fc + (size_t)brow * NH + k0 + sc;
        float4 bf0 = *(const float4*)bp, bf1 = *(const float4*)(bp + 4);
        *(uint4*)(Ash + sr * LDP + sc) =
            *(const uint4*)(hs + (size_t)(m0 + sr) * NH + k0 + sc);
        *(uint4*)(Bsh + sr * LDP + sc) = pack8(bf0, bf1);
        __syncthreads();
        bf16x8 a0 = *(const bf16x8*)(Ash + (wm + fr) * LDP + kq * 8);
        bf16x8 a1 = *(const bf16x8*)(Ash + (wm + 16 + fr) * LDP + kq * 8);
        bf16x8 b0 = *(const bf16x8*)(Bsh + (wn + fr) * LDP + kq * 8);
        bf16x8 b1 = *(const bf16x8*)(Bsh + (wn + 16 + fr) * LDP + kq * 8);
        acc[0][0] = __builtin_amdgcn_mfma_f32_16x16x32_bf16(a0, b0, acc[0][0], 0, 0, 0);
        acc[0][1] = __builtin_amdgcn_mfma_f32_16x16x32_bf16(a0, b1, acc[0][1], 0, 0, 0);
        acc[1][0] = __builtin_amdgcn_mfma_f32_16x16x32_bf16(a1, b0, acc[1][0], 0, 0, 0);
        acc[1][1] = __builtin_amdgcn_mfma_f32_16x16x32_bf16(a1, b1, acc[1][1], 0, 0, 0);
        __syncthreads();
    }

    for (int i = 0; i < 2; ++i)
        for (int j = 0; j < 2; ++j) {
            const int row = m0 + wm + i * 16 + kq * 4;
            const int col = n0 + wn + j * 16 + fr;
            if (col < NV) {
                const float bias = b_fc[col];
                for (int r = 0; r < 4; ++r)
                    out[(size_t)(row + r) * NV + col] = acc[i][j][r] + bias;
            }
        }
}

// =====================================================================
extern "C" void kernel_launch(void* const* d_in, const int* in_sizes, int n_in,
                              void* d_out, int out_size, void* d_ws, size_t ws_size,
                              hipStream_t stream)
{
    const int*   x    = (const int*)d_in[0];
    const float* emb  = (const float*)d_in[1];
    const float* W_ih = (const float*)d_in[2];
    const float* W_hh = (const float*)d_in[3];
    const float* b_ih = (const float*)d_in[4];
    const float* b_hh = (const float*)d_in[5];
    const float* W_fc = (const float*)d_in[6];
    const float* b_fc = (const float*)d_in[7];
    float*       out  = (float*)d_out;

    // workspace: xg bf16 (134.2MB) | hs bf16 (33.6MB) | c fp32 (128KB)
    char* w = (char*)d_ws;
    const size_t XG_BYTES = (size_t)NB * NS * NG * 2;
    const size_t HS_BYTES = (size_t)NB * NS * NH * 2;
    unsigned short* xg  = (unsigned short*)w;
    unsigned short* hsb = (unsigned short*)(w + XG_BYTES);
    float*          c   = (float*)(w + XG_BYTES + HS_BYTES);

    k_embed_gemm<<<dim3(NG / 64, (NB * NS) / 64), 256, 0, stream>>>(
        x, emb, W_ih, b_ih, b_hh, xg);

    for (int t = 0; t < NS; ++t)
        k_lstm_step<<<dim3(NH / 4), 256, 0, stream>>>(xg, W_hh, hsb, c, t);

    k_logits_gemm<<<dim3((NV + 63) / 64, (NB * NS) / 64), 256, 0, stream>>>(
        hsb, W_fc, b_fc, out);
}